// Round 6
// baseline (123.527 us; speedup 1.0000x reference)
//
#include <hip/hip_runtime.h>
#include <hip/hip_bf16.h>
#include <math.h>

// Shapes
#define QL 32768
#define DD 1024
#define NTOK 64

using short8   = __attribute__((ext_vector_type(8))) short;
using f32x4    = __attribute__((ext_vector_type(4))) float;
using float4v  = __attribute__((ext_vector_type(4))) float;
using ushort4v = __attribute__((ext_vector_type(4))) unsigned short;
using ushort8v = __attribute__((ext_vector_type(8))) unsigned short;

// RNE f32->bf16 via bit trick (exact RNE)
__device__ __forceinline__ unsigned short f2bf(float f) {
    unsigned int u = __float_as_uint(f);
    unsigned int r = (u + 0x7FFFu + ((u >> 16) & 1u)) >> 16;
    return (unsigned short)r;
}

// async global->LDS, 16B per lane; dest = wave-uniform base + lane*16
__device__ __forceinline__ void gload_lds16(const void* g, void* l) {
    __builtin_amdgcn_global_load_lds(
        (const __attribute__((address_space(1))) void*)g,
        (__attribute__((address_space(3))) void*)l,
        16, 0, 0);
}

// ---------------------------------------------------------------------------
// Prologue 1: transpose-convert Wq (1024x1024) -> WqT bf16, Pv (64x1024) -> PvT bf16.
// ---------------------------------------------------------------------------
__global__ __launch_bounds__(256) void prep_transpose_kernel(
        const float* __restrict__ Wq, const float* __restrict__ Pv,
        unsigned short* __restrict__ WqT, unsigned short* __restrict__ PvT) {
    __shared__ float tile[64][65];
    int b = blockIdx.x;
    const float* src; unsigned short* dst; int R, C, r0, c0;
    if (b < 256) { src = Wq; dst = WqT; R = 1024; C = 1024;
                   r0 = (b >> 4) << 6; c0 = (b & 15) << 6; }
    else         { b -= 256; src = Pv; dst = PvT; R = 64; C = 1024;
                   r0 = 0; c0 = b << 6; }
    const int tid = threadIdx.x;
#pragma unroll
    for (int i = 0; i < 16; ++i) {
        const int lin = tid + 256 * i;
        const int row = lin >> 6, col = lin & 63;
        if (r0 + row < R)
            tile[row][col] = src[(size_t)(r0 + row) * C + c0 + col];
    }
    __syncthreads();
#pragma unroll
    for (int i = 0; i < 16; ++i) {
        const int lin = tid + 256 * i;
        const int row = lin >> 6, col = lin & 63;
        if (r0 + col < R)
            dst[(size_t)(c0 + row) * R + r0 + col] = f2bf(tile[col][row]);
    }
}

// ---------------------------------------------------------------------------
// Prologue 2: Kp = Pk @ Wq via bf16 MFMA (B from WqT). grid 16 x 256.
// ---------------------------------------------------------------------------
__global__ __launch_bounds__(256) void kp_mfma_kernel(
        const float* __restrict__ Pk, const unsigned short* __restrict__ WqT,
        unsigned short* __restrict__ Kp) {
    const int tid = threadIdx.x;
    const int w   = tid >> 6;
    const int l   = tid & 63;
    const int lhi = l >> 4;
    const int llo = l & 15;
    const int N0  = blockIdx.x * 64;

    f32x4 acc[4];
#pragma unroll
    for (int ct = 0; ct < 4; ++ct) acc[ct] = (f32x4){0.f, 0.f, 0.f, 0.f};

    for (int kb = 0; kb < 32; ++kb) {
        const int k0 = kb * 32 + lhi * 8;
        float4v p0 = *(const float4v*)(Pk + (size_t)(w * 16 + llo) * DD + k0);
        float4v p1 = *(const float4v*)(Pk + (size_t)(w * 16 + llo) * DD + k0 + 4);
        short8 a;
        a[0] = (short)f2bf(p0.x); a[1] = (short)f2bf(p0.y);
        a[2] = (short)f2bf(p0.z); a[3] = (short)f2bf(p0.w);
        a[4] = (short)f2bf(p1.x); a[5] = (short)f2bf(p1.y);
        a[6] = (short)f2bf(p1.z); a[7] = (short)f2bf(p1.w);
#pragma unroll
        for (int ct = 0; ct < 4; ++ct) {
            short8 b = *(const short8*)(WqT + (size_t)(N0 + ct * 16 + llo) * DD + k0);
            acc[ct] = __builtin_amdgcn_mfma_f32_16x16x32_bf16(a, b, acc[ct], 0, 0, 0);
        }
    }
#pragma unroll
    for (int ct = 0; ct < 4; ++ct) {
#pragma unroll
        for (int j = 0; j < 4; ++j) {
            const int t = w * 16 + lhi * 4 + j;
            const int d = N0 + ct * 16 + llo;
            Kp[(size_t)t * DD + d] = f2bf(acc[ct][j]);
        }
    }
}

// ---------------------------------------------------------------------------
// GEMM1: s' = gelu(l2norm_scale(x @ Kp^T)) -> bf16 [32768][64].
// grid 2048 x 256 (4 waves). Block = 16 q-rows, K = 4 tiles of 256 f32.
// Staging: global_load_lds dwordx4, double-buffered (T3 2-phase recipe).
//   LDS tile fp32 [16 rows][64 chunks of 16B], chunk-XOR swizzle:
//   LDS[r][c] holds global chunk (r, c ^ (r&7))  (linear dest, pre-swizzled src).
// Compute: wave w owns k-quarter [w*64, w*64+64) f32 of every tile.
// Reduce: sPart aliased onto staging LDS after the last tile.
// ---------------------------------------------------------------------------
__global__ __launch_bounds__(256) void gemm1_kernel(
        const float* __restrict__ x, const unsigned short* __restrict__ Kp,
        unsigned short* __restrict__ sp) {
    __shared__ __align__(16) unsigned char sX[2][16384];

    const int tid = threadIdx.x;
    const int w   = tid >> 6;
    const int l   = tid & 63;
    const int lhi = l >> 4;    // 0..3
    const int llo = l & 15;    // 0..15
    const int R0  = blockIdx.x * 16;
    const char* xbase = (const char*)x + (size_t)R0 * 4096;

    f32x4 acc[4];
#pragma unroll
    for (int ct = 0; ct < 4; ++ct) acc[ct] = (f32x4){0.f, 0.f, 0.f, 0.f};

    // stage tile t into buffer b: instr j stages row r = w*4+j (1KB);
    // lane l -> LDS chunk (r, l) <- global chunk (r, l ^ (r&7)) of the tile
#define STAGE(t, b)                                                             \
    {                                                                           \
        _Pragma("unroll")                                                       \
        for (int j = 0; j < 4; ++j) {                                           \
            const int r   = w * 4 + j;                                          \
            const int csw = l ^ (r & 7);                                        \
            gload_lds16(xbase + (size_t)r * 4096 + (t) * 1024 + csw * 16,       \
                        (void*)(sX[b] + r * 1024 + 0));                         \
        }                                                                       \
    }
// NOTE: LDS base passed is row base; HW adds lane*16 -> chunk l. (wave-uniform base)

#define COMPUTE(t, b)                                                           \
    {                                                                           \
        _Pragma("unroll")                                                       \
        for (int ks = 0; ks < 2; ++ks) {                                        \
            const int c0 = w * 16 + ks * 8 + lhi * 2;                           \
            const int sw = llo & 7;                                             \
            const float4v f0 = *(const float4v*)(sX[b] + llo * 1024 + ((c0 ^ sw) << 4));       \
            const float4v f1 = *(const float4v*)(sX[b] + llo * 1024 + (((c0 + 1) ^ sw) << 4)); \
            short8 a;                                                           \
            ((__hip_bfloat162*)&a)[0] = __float22bfloat162_rn(float2{f0.x, f0.y}); \
            ((__hip_bfloat162*)&a)[1] = __float22bfloat162_rn(float2{f0.z, f0.w}); \
            ((__hip_bfloat162*)&a)[2] = __float22bfloat162_rn(float2{f1.x, f1.y}); \
            ((__hip_bfloat162*)&a)[3] = __float22bfloat162_rn(float2{f1.z, f1.w}); \
            const int kg = (t) * 256 + w * 64 + ks * 32 + lhi * 8;              \
            _Pragma("unroll")                                                   \
            for (int ct = 0; ct < 4; ++ct) {                                    \
                short8 bb = *(const short8*)(Kp + (size_t)(ct * 16 + llo) * DD + kg); \
                acc[ct] = __builtin_amdgcn_mfma_f32_16x16x32_bf16(a, bb, acc[ct], 0, 0, 0); \
            }                                                                   \
        }                                                                       \
    }

    STAGE(0, 0);
    __syncthreads();                 // compiler drains vmcnt before s_barrier
    STAGE(1, 1);
    COMPUTE(0, 0);
    __syncthreads();
    STAGE(2, 0);
    COMPUTE(1, 1);
    __syncthreads();
    STAGE(3, 1);
    COMPUTE(2, 0);
    __syncthreads();
    COMPUTE(3, 1);
    __syncthreads();                 // all reads of sX done -> safe to alias
#undef STAGE
#undef COMPUTE

    // ---- cross-wave reduce + row l2-norm*8 + exact GELU -> sp ----
    float (*sPart)[16][68] = (float (*)[16][68])(void*)sX;   // 17.4 KB alias
#pragma unroll
    for (int ct = 0; ct < 4; ++ct)
#pragma unroll
        for (int j = 0; j < 4; ++j)
            sPart[w][lhi * 4 + j][ct * 16 + llo] = acc[ct][j];
    __syncthreads();

    {
        const int r  = tid >> 4;          // 0..15
        const int cb = (tid & 15) * 4;    // 0..60
        f32x4 v  = *(const f32x4*)&sPart[0][r][cb];
        f32x4 v1 = *(const f32x4*)&sPart[1][r][cb];
        f32x4 v2 = *(const f32x4*)&sPart[2][r][cb];
        f32x4 v3 = *(const f32x4*)&sPart[3][r][cb];
        v = v + v1 + v2 + v3;
        float ssq = v.x * v.x + v.y * v.y + v.z * v.z + v.w * v.w;
        ssq += __shfl_xor(ssq, 1);
        ssq += __shfl_xor(ssq, 2);
        ssq += __shfl_xor(ssq, 4);
        ssq += __shfl_xor(ssq, 8);
        const float scale = 8.0f / sqrtf(ssq);
        ushort4v g;
#pragma unroll
        for (int k = 0; k < 4; ++k) {
            const float vv = v[k] * scale;
            const float ge = 0.5f * vv * (1.0f + erff(vv * 0.70710678118654752f));
            g[k] = f2bf(ge);
        }
        *(ushort4v*)(sp + (size_t)(R0 + r) * 64 + cb) = g;
    }
}

// ---------------------------------------------------------------------------
// GEMM2: y[32768][1024] = s'(bf16) @ Pv, swapped MFMA (D[m=d][n=q]),
// float4 stores. grid 2048 x 256 (4 waves); block = 16 q-rows; wave = 256 d-cols.
// ---------------------------------------------------------------------------
__global__ __launch_bounds__(256, 4) void gemm2_kernel(
        const unsigned short* __restrict__ sp, const unsigned short* __restrict__ PvT,
        float* __restrict__ out) {
    __shared__ __align__(16) unsigned char sS[16 * 128];  // s' [16][64] bf16 swizzled

    const int tid = threadIdx.x;
    const int w   = tid >> 6;
    const int l   = tid & 63;
    const int lhi = l >> 4;
    const int llo = l & 15;
    const int R0  = blockIdx.x * 16;

    // stage s' tile (2KB) coalesced, swizzled
    if (tid < 128) {
        const int o = tid * 16;             // flat byte in [16][128]
        const int q = o >> 7;
        ushort8v v = *(const ushort8v*)(sp + (size_t)R0 * 64 + tid * 8);
        *(ushort8v*)(sS + (o ^ ((q & 7) << 4))) = v;
    }
    __syncthreads();

    short8 sb0 = *(const short8*)(sS + ((llo * 128 + lhi * 16)      ^ ((llo & 7) << 4)));
    short8 sb1 = *(const short8*)(sS + ((llo * 128 + 64 + lhi * 16) ^ ((llo & 7) << 4)));

    const int N0w = w * 256;
    float* orow = out + (size_t)(R0 + llo) * DD + N0w + lhi * 4;
#pragma unroll 4
    for (int dt = 0; dt < 16; ++dt) {
        const unsigned short* ap = PvT + (size_t)(N0w + dt * 16 + llo) * 64 + lhi * 8;
        short8 pa0 = *(const short8*)ap;
        short8 pa1 = *(const short8*)(ap + 32);
        f32x4 acc2 = (f32x4){0.f, 0.f, 0.f, 0.f};
        acc2 = __builtin_amdgcn_mfma_f32_16x16x32_bf16(pa0, sb0, acc2, 0, 0, 0);
        acc2 = __builtin_amdgcn_mfma_f32_16x16x32_bf16(pa1, sb1, acc2, 0, 0, 0);
        *(float4v*)(orow + dt * 16) = acc2;
    }
}

// ---------------------------------------------------------------------------
extern "C" void kernel_launch(void* const* d_in, const int* in_sizes, int n_in,
                              void* d_out, int out_size, void* d_ws, size_t ws_size,
                              hipStream_t stream) {
    (void)in_sizes; (void)n_in; (void)out_size; (void)ws_size;
    const float* x  = (const float*)d_in[0];
    const float* Wq = (const float*)d_in[1];
    const float* Pk = (const float*)d_in[2];
    const float* Pv = (const float*)d_in[3];
    float* out = (float*)d_out;

    // ws layout (6.25 MB total):
    //   WqT bf16 [1024][1024] @ 0            (2 MB)
    //   Kp  bf16 [64][1024]   @ 2 MB         (128 KB)
    //   PvT bf16 [1024][64]   @ 2 MB + 128K  (128 KB)
    //   s'  bf16 [32768][64]  @ 2.25 MB      (4 MB)
    unsigned short* WqT = (unsigned short*)d_ws;
    unsigned short* Kp  = (unsigned short*)((char*)d_ws + 2097152);
    unsigned short* PvT = (unsigned short*)((char*)d_ws + 2097152 + 131072);
    unsigned short* sp  = (unsigned short*)((char*)d_ws + 2097152 + 262144);

    prep_transpose_kernel<<<272, 256, 0, stream>>>(Wq, Pv, WqT, PvT);
    kp_mfma_kernel<<<16, 256, 0, stream>>>(Pk, WqT, Kp);
    gemm1_kernel<<<2048, 256, 0, stream>>>(x, Kp, sp);
    gemm2_kernel<<<2048, 256, 0, stream>>>(sp, PvT, out);
}